// Round 5
// baseline (173.112 us; speedup 1.0000x reference)
//
#include <hip/hip_runtime.h>

#define BATCH 4096
#define N 64

// One DPP max-reduce step: x = max(x, dpp_move(x)). No DS ops, no waits.
template<int CTRL>
__device__ __forceinline__ float dpp_max_step(float x) {
    int moved = __builtin_amdgcn_update_dpp(0, __float_as_int(x), CTRL, 0xf, 0xf, true);
    return fmaxf(x, __int_as_float(moved));
}

// Broadcast a float from wave-uniform lane ps: v_readlane -> SGPR, folds as
// scalar operand into the consuming v_fma.
__device__ __forceinline__ float lanebcast(float v, int ps) {
    return __uint_as_float(__builtin_amdgcn_readlane(__float_as_uint(v), ps));
}

// Zero-cost register-class pin: forces the value into an ARCH VGPR (class
// VGPR_32, not the AV_32 vgpr-or-agpr class). Round-3/4 evidence: without
// this, regalloc parks a[64] in AGPRs (VGPR_Count=40) and every element
// pays v_accvgpr_read/write round-trips (~3x instruction inflation).
#define PIN_V(x) asm("" : "+v"(x))

__global__ __launch_bounds__(64, 1) void restricted_det_kernel(
    const float* __restrict__ U,
    const int* __restrict__ idx_up,
    const int* __restrict__ idx_dn,
    float* __restrict__ out)
{
    const int lane = threadIdx.x;      // 0..63, one wave per block
    const int wid  = blockIdx.x;       // sample id, exact cover of BATCH

    const int site0 = idx_up[wid * N + lane];
    const int site1 = idx_dn[wid * N + lane];

    float l2sum = 0.0f;           // sum of log2|pivot| over both dets
    unsigned int sbits = 0u;      // xor of pivot sign bits (wave-uniform)
    int inv = 0;                  // permutation inversion count (wave-uniform)

    #pragma unroll 1
    for (int spin = 0; spin < 2; ++spin) {
        const int site = (spin == 0) ? site0 : site1;

        // lane i holds row i of the gathered matrix, in registers
        float a[N];
        const float4* __restrict__ row = reinterpret_cast<const float4*>(U + (long)site * N);
        #pragma unroll
        for (int q = 0; q < N / 4; ++q) {
            float4 v = row[q];
            a[4*q+0] = v.x; a[4*q+1] = v.y; a[4*q+2] = v.z; a[4*q+3] = v.w;
            PIN_V(a[4*q+0]); PIN_V(a[4*q+1]); PIN_V(a[4*q+2]); PIN_V(a[4*q+3]);
        }

        unsigned long long chosen = 0ull;  // uniform: rows already used as pivot
        bool alive = true;                 // per-lane: row not yet pivoted

        #pragma unroll
        for (int k = 0; k < N; ++k) {
            // ---- pivot = argmax |a[k]| over live lanes (DPP tree, 6 steps) ----
            const float key = alive ? __builtin_fabsf(a[k]) : -1.0f;
            float r = key;
            r = dpp_max_step<0x111>(r);   // row_shr:1
            r = dpp_max_step<0x112>(r);   // row_shr:2
            r = dpp_max_step<0x114>(r);   // row_shr:4
            r = dpp_max_step<0x118>(r);   // row_shr:8   -> lane15 of each row-of-16
            r = dpp_max_step<0x142>(r);   // row_bcast15 -> lane31/63 merge prev row
            r = dpp_max_step<0x143>(r);   // row_bcast31 -> lane63 = wave max
            const float mx = __uint_as_float(
                __builtin_amdgcn_readlane(__float_as_uint(r), 63));  // SGPR
            const unsigned long long bal = __ballot(key == mx);      // live lanes only
            const int ps = (int)__builtin_ctzll(bal);                // uniform pivot lane

            // ---- parity via inversion counting (SALU) ----
            inv += __popcll(chosen >> ps);
            chosen |= (1ull << ps);
            alive = alive && (lane != ps);

            // ---- pivot value: sign (SALU xor), log-magnitude (|pv| == mx) ----
            const float pv = lanebcast(a[k], ps);
            sbits ^= __float_as_uint(pv);
            l2sum += __log2f(mx);

            // ---- rank-1 trailing update; dead/pivot lanes free-run on garbage
            //      (safe: each pivot-row elem is readlane'd before lane ps
            //       overwrites it, and dead rows are never selected again) ----
            const float rm = __builtin_amdgcn_rcpf(pv);
            const float m  = a[k] * rm;
            #pragma unroll
            for (int j = k + 1; j < N; ++j) {
                PIN_V(a[j]);                            // keep in arch VGPR
                const float uv = lanebcast(a[j], ps);   // SGPR scalar operand
                a[j] = __builtin_fmaf(-m, uv, a[j]);
            }
        }
    }

    if (lane == 0) {
        const float sgn =
            (((sbits >> 31) ^ ((unsigned)inv & 1u)) != 0u) ? -1.0f : 1.0f;
        out[wid] = sgn;                                        // sign_up * sign_dn
        out[BATCH + wid] = l2sum * 0.69314718055994530942f;    // ln from log2
    }
}

extern "C" void kernel_launch(void* const* d_in, const int* in_sizes, int n_in,
                              void* d_out, int out_size, void* d_ws, size_t ws_size,
                              hipStream_t stream) {
    const float* U      = (const float*)d_in[0];
    const int*   idx_up = (const int*)d_in[1];
    const int*   idx_dn = (const int*)d_in[2];
    float* out = (float*)d_out;

    dim3 block(64);                  // one wave per block, 1 sample per wave
    dim3 grid(BATCH);                // 4096 waves, exact cover
    hipLaunchKernelGGL(restricted_det_kernel, grid, block, 0, stream,
                       U, idx_up, idx_dn, out);
}